// Round 1
// baseline (992.100 us; speedup 1.0000x reference)
//
#include <hip/hip_runtime.h>
#include <math.h>

#define KK 9
#define NB 4
#define NC 64
#define NO 64
#define NH 128
#define HP 136
#define NPIX (NH*NH)     /* 16384 */
#define PADPIX (HP*HP)   /* 18496 */
#define NCH 18

/* workspace layout (float offsets) */
#define SZ_FP    (NB*NC*PADPIX)        /* 4,734,976 */
#define O_FPCHW  0
#define O_FPFLAT (O_FPCHW + SZ_FP)
#define O_OFF    (O_FPFLAT + SZ_FP)
#define SZ_OFF   (NB*NCH*NPIX)         /* 1,179,648 */
#define O_STATS  (O_OFF + SZ_OFF)
#define O_WX     (O_STATS + 64)
#define O_WY     (O_WX + KK*64*64)
#define O_R2     (O_WY + KK*64*64)
#define SZ_R     (NB*KK*NPIX)          /* 589,824 */
#define O_R3     (O_R2 + SZ_R)
#define WS_FLOATS (O_R3 + SZ_R)        /* ~11.9M floats = 47.6 MB */

__global__ void k_zero(float4* p, int n4) {
    int id = blockIdx.x * 256 + threadIdx.x;
    if (id < n4) p[id] = make_float4(0.f, 0.f, 0.f, 0.f);
}

/* fill both padded layouts of f */
__global__ void k_pad(const float* __restrict__ f, float* __restrict__ fpchw,
                      float* __restrict__ fpflat) {
    int id = blockIdx.x * 256 + threadIdx.x;
    if (id >= NB * NC * NPIX) return;
    int w = id & 127;
    int h = (id >> 7) & 127;
    int c = (id >> 14) & 63;
    int b = id >> 20;
    float v = f[id];
    fpchw[((b * NC + c) * HP + (h + 4)) * HP + (w + 4)] = v;
    fpflat[(((b * HP + (h + 4)) * HP) + (w + 4)) * NC + c] = v;
}

/* transpose main-conv weights to [k][c][o] */
__global__ void k_wt(const float* __restrict__ cwx, const float* __restrict__ cwy,
                     float* __restrict__ wx, float* __restrict__ wy) {
    int id = blockIdx.x * 256 + threadIdx.x;
    if (id >= KK * 64 * 64) return;
    int o = id & 63;
    int c = (id >> 6) & 63;
    int k = id >> 12;
    wx[id] = cwx[(o * 64 + c) * 9 + k];
    wy[id] = cwy[(o * 64 + c) * 9 + k];
}

/* offset conv: (B,18,128,128); per-c fp32 partial accumulated in double */
__global__ __launch_bounds__(128) void k_off(const float* __restrict__ fpchw,
                                             const float* __restrict__ offw,
                                             const float* __restrict__ offb,
                                             float* __restrict__ off) {
    int co = blockIdx.x, i = blockIdx.y, b = blockIdx.z, j = threadIdx.x;
    const float* wbase = offw + co * 64 * 81;
    double tot = 0.0;
    for (int c = 0; c < 64; ++c) {
        const float* fr = fpchw + ((size_t)((b * 64 + c) * HP + i)) * HP + j;
        const float* wp = wbase + c * 81;
        float pc = 0.f;
#pragma unroll
        for (int ky = 0; ky < 9; ++ky) {
            const float* r = fr + ky * HP;
#pragma unroll
            for (int kx = 0; kx < 9; ++kx)
                pc = fmaf(r[kx], wp[ky * 9 + kx], pc);
        }
        tot += (double)pc;
    }
    off[((b * NCH + co) << 14) + (i << 7) + j] = (float)tot + offb[co];
}

/* per-channel mean / rsqrt(var+eps) in double */
__global__ __launch_bounds__(256) void k_stats(const float* __restrict__ off,
                                               float* __restrict__ stats) {
    int ch = blockIdx.x, t = threadIdx.x;
    double s = 0.0, ss = 0.0;
    for (int p = t; p < NB * NPIX; p += 256) {
        int b = p >> 14, q = p & 16383;
        float v = off[((b * NCH + ch) << 14) + q];
        s += (double)v;
        ss += (double)v * (double)v;
    }
    __shared__ double sh1[256], sh2[256];
    sh1[t] = s; sh2[t] = ss;
    __syncthreads();
    for (int st = 128; st > 0; st >>= 1) {
        if (t < st) { sh1[t] += sh1[t + st]; sh2[t] += sh2[t + st]; }
        __syncthreads();
    }
    if (t == 0) {
        double n = (double)(NB * NPIX);
        double m = sh1[0] / n;
        double var = sh2[0] / n - m * m;
        stats[ch] = (float)m;
        stats[NCH + ch] = (float)(1.0 / sqrt(var + 1e-5));
    }
}

/* BN + tanh + cum + floor -> gather row indices (reproduces base-stride bug) */
__global__ __launch_bounds__(128) void k_idx(const float* __restrict__ off,
                                             const float* __restrict__ stats,
                                             const float* __restrict__ gamma,
                                             const float* __restrict__ beta,
                                             int* __restrict__ r2, int* __restrict__ r3) {
    int i = blockIdx.x, b = blockIdx.y, j = threadIdx.x;
    float tt[NCH];
#pragma unroll
    for (int ch = 0; ch < NCH; ++ch) {
        float v = off[((b * NCH + ch) << 14) + (i << 7) + j];
        v = (v - stats[ch]) * stats[NCH + ch];
        v = v * gamma[ch] + beta[ch];
        tt[ch] = (float)tanh((double)v);
    }
    /* cum(): [0, h1, h2, h3, mid, t5, t6, t7, 0] with reference association */
    float cz[9], cw[9];
    {
        const float* o = tt;
        cz[0] = 0.f;
        cz[1] = o[1];
        cz[2] = o[1] + o[2];
        cz[3] = (o[1] + o[2]) + o[3];
        cz[7] = o[7];
        cz[6] = o[7] + o[6];
        cz[5] = (o[7] + o[6]) + o[5];
        cz[4] = (cz[3] + cz[5]) * 0.5f;
        cz[8] = 0.f;
    }
    {
        const float* o = tt + 9;
        cw[0] = 0.f;
        cw[1] = o[1];
        cw[2] = o[1] + o[2];
        cw[3] = (o[1] + o[2]) + o[3];
        cw[7] = o[7];
        cw[6] = o[7] + o[6];
        cw[5] = (o[7] + o[6]) + o[5];
        cw[4] = (cw[3] + cw[5]) * 0.5f;
        cw[8] = 0.f;
    }
    const int rmax = NB * PADPIX - 1;
#pragma unroll
    for (int k = 0; k < 9; ++k) {
        /* y2 = (yc + g_desc) + cz ; x2 = (xc + g_asc) + cz */
        int iy2 = (int)floorf((float)(i + 8 - k) + cz[k]);
        int ix2 = (int)floorf((float)(j + k) + cz[k]);
        int rr = b * 16384 + iy2 * HP + ix2;
        rr = rr < 0 ? 0 : (rr > rmax ? rmax : rr);
        r2[((b * 9 + k) << 14) + (i << 7) + j] = rr;
        /* y3 = (yc + g_asc) + cw ; x3 = (xc + g_asc) - cw */
        int iy3 = (int)floorf((float)(i + k) + cw[k]);
        int ix3 = (int)floorf((float)(j + k) - cw[k]);
        int r3v = b * 16384 + iy3 * HP + ix3;
        r3v = r3v < 0 ? 0 : (r3v > rmax ? rmax : r3v);
        r3[((b * 9 + k) << 14) + (i << 7) + j] = r3v;
    }
}

/* main gathered strip-convs: per block 64 positions x 64 out-ch, Kdim = 18*64 */
__global__ __launch_bounds__(256) void k_main(const float* __restrict__ fpflat,
                                              const int* __restrict__ r2,
                                              const int* __restrict__ r3,
                                              const float* __restrict__ wx,
                                              const float* __restrict__ wy,
                                              const float* __restrict__ bx,
                                              const float* __restrict__ by,
                                              float* __restrict__ out) {
    __shared__ float sA[64 * 64];  /* [c][j] */
    __shared__ float sW[64 * 64];  /* [c][o] */
    int b = blockIdx.z, i = blockIdx.y;
    int j0 = blockIdx.x * 64;
    int t = threadIdx.x;
    int jt = t & 15;   /* j-group: j0 + jt*4 .. +3 */
    int ot = t >> 4;   /* o-group: ot*4 .. +3 */
    float acc[4][4];
#pragma unroll
    for (int a = 0; a < 4; ++a)
#pragma unroll
        for (int bb = 0; bb < 4; ++bb) acc[a][bb] = 0.f;

    int sj = t >> 2;       /* staging: 4 threads per position */
    int cq = t & 3;

    for (int q = 0; q < 18; ++q) {
        int k = (q < 9) ? q : (q - 9);
        const int* rr = ((q < 9) ? r2 : r3) + (((b * 9 + k) << 14) + (i << 7) + j0);
        const float* wsrc = ((q < 9) ? wx : wy) + k * 4096;
        __syncthreads();
        /* stage W tile: 4096 floats */
        {
            const float4* s4 = (const float4*)wsrc;
            float4* d4 = (float4*)sW;
#pragma unroll
            for (int u = 0; u < 4; ++u) d4[t + 256 * u] = s4[t + 256 * u];
        }
        /* stage A tile, transposed to [c][j] */
        {
            int row = rr[sj];
            const float* src = fpflat + (size_t)row * 64;
#pragma unroll
            for (int u = 0; u < 4; ++u) {
                int c0 = cq * 16 + u * 4;
                float4 v = *(const float4*)(src + c0);
                sA[(c0 + 0) * 64 + sj] = v.x;
                sA[(c0 + 1) * 64 + sj] = v.y;
                sA[(c0 + 2) * 64 + sj] = v.z;
                sA[(c0 + 3) * 64 + sj] = v.w;
            }
        }
        __syncthreads();
#pragma unroll 4
        for (int c = 0; c < 64; ++c) {
            float4 a4 = *(const float4*)&sA[c * 64 + jt * 4];
            float4 w4 = *(const float4*)&sW[c * 64 + ot * 4];
            const float av[4] = {a4.x, a4.y, a4.z, a4.w};
            const float wv[4] = {w4.x, w4.y, w4.z, w4.w};
#pragma unroll
            for (int jj = 0; jj < 4; ++jj)
#pragma unroll
                for (int oo = 0; oo < 4; ++oo)
                    acc[jj][oo] = fmaf(av[jj], wv[oo], acc[jj][oo]);
        }
    }
#pragma unroll
    for (int oo = 0; oo < 4; ++oo) {
        int o = ot * 4 + oo;
        float bias = bx[o] + by[o];
#pragma unroll
        for (int jj = 0; jj < 4; ++jj) {
            int j = j0 + jt * 4 + jj;
            out[(((b * NO + o) << 7) + i) * NH + j] = acc[jj][oo] + bias;
        }
    }
}

extern "C" void kernel_launch(void* const* d_in, const int* in_sizes, int n_in,
                              void* d_out, int out_size, void* d_ws, size_t ws_size,
                              hipStream_t stream) {
    const float* f     = (const float*)d_in[0];
    const float* offw  = (const float*)d_in[1];
    const float* offb  = (const float*)d_in[2];
    const float* gamma = (const float*)d_in[3];
    const float* beta  = (const float*)d_in[4];
    const float* cwx   = (const float*)d_in[5];
    const float* cbx   = (const float*)d_in[6];
    const float* cwy   = (const float*)d_in[7];
    const float* cby   = (const float*)d_in[8];
    float* ws = (float*)d_ws;
    float* fpchw  = ws + O_FPCHW;
    float* fpflat = ws + O_FPFLAT;
    float* off    = ws + O_OFF;
    float* stats  = ws + O_STATS;
    float* wx     = ws + O_WX;
    float* wy     = ws + O_WY;
    int*   r2     = (int*)(ws + O_R2);
    int*   r3     = (int*)(ws + O_R3);
    float* out    = (float*)d_out;

    /* zero the two padded arrays (ws is poisoned before every launch) */
    {
        int n4 = (2 * SZ_FP) / 4;
        k_zero<<<(n4 + 255) / 256, 256, 0, stream>>>((float4*)fpchw, n4);
    }
    k_pad<<<(NB * NC * NPIX + 255) / 256, 256, 0, stream>>>(f, fpchw, fpflat);
    k_wt<<<(KK * 64 * 64 + 255) / 256, 256, 0, stream>>>(cwx, cwy, wx, wy);
    k_off<<<dim3(NCH, NH, NB), 128, 0, stream>>>(fpchw, offw, offb, off);
    k_stats<<<NCH, 256, 0, stream>>>(off, stats);
    k_idx<<<dim3(NH, NB), 128, 0, stream>>>(off, stats, gamma, beta, r2, r3);
    k_main<<<dim3(2, NH, NB), 256, 0, stream>>>(fpflat, r2, r3, wx, wy, cbx, cby, out);
}

// Round 2
// 710.499 us; speedup vs baseline: 1.3963x; 1.3963x over previous
//
#include <hip/hip_runtime.h>
#include <math.h>

#define KK 9
#define NB 4
#define NC 64
#define NO 64
#define NH 128
#define HP 136
#define NPIX (NH*NH)     /* 16384 */
#define PADPIX (HP*HP)   /* 18496 */
#define NCH 18
#define CO_PER 6         /* offset-conv output channels per block */

/* workspace layout (float offsets) */
#define SZ_FP    (NB*NC*PADPIX)        /* 4,734,976 */
#define O_FPCHW  0
#define O_FPFLAT (O_FPCHW + SZ_FP)
#define O_OFF    (O_FPFLAT + SZ_FP)
#define SZ_OFF   (NB*NCH*NPIX)         /* 1,179,648 */
#define O_STATS  (O_OFF + SZ_OFF)
#define O_WX     (O_STATS + 64)
#define O_WY     (O_WX + KK*64*64)
#define O_R2     (O_WY + KK*64*64)
#define SZ_R     (NB*KK*NPIX)          /* 589,824 */
#define O_R3     (O_R2 + SZ_R)
#define WS_FLOATS (O_R3 + SZ_R)        /* ~11.9M floats = 47.6 MB */

__global__ void k_zero(float4* p, int n4) {
    int id = blockIdx.x * 256 + threadIdx.x;
    if (id < n4) p[id] = make_float4(0.f, 0.f, 0.f, 0.f);
}

/* fill both padded layouts of f */
__global__ void k_pad(const float* __restrict__ f, float* __restrict__ fpchw,
                      float* __restrict__ fpflat) {
    int id = blockIdx.x * 256 + threadIdx.x;
    if (id >= NB * NC * NPIX) return;
    int w = id & 127;
    int h = (id >> 7) & 127;
    int c = (id >> 14) & 63;
    int b = id >> 20;
    float v = f[id];
    fpchw[((b * NC + c) * HP + (h + 4)) * HP + (w + 4)] = v;
    fpflat[(((b * HP + (h + 4)) * HP) + (w + 4)) * NC + c] = v;
}

/* transpose main-conv weights to [k][c][o] */
__global__ void k_wt(const float* __restrict__ cwx, const float* __restrict__ cwy,
                     float* __restrict__ wx, float* __restrict__ wy) {
    int id = blockIdx.x * 256 + threadIdx.x;
    if (id >= KK * 64 * 64) return;
    int o = id & 63;
    int c = (id >> 6) & 63;
    int k = id >> 12;
    wx[id] = cwx[(o * 64 + c) * 9 + k];
    wy[id] = cwy[(o * 64 + c) * 9 + k];
}

/* offset conv, LDS-staged: block = (co-group of 6, row i, batch b), 128 thr = j.
   Per channel c: stage the contiguous 9x136 slab (306 float4) into LDS,
   prefetched into registers during the previous channel's compute.
   Per-(co,c) fp32 tap chain in (ky,kx) order, double-accumulated over c
   in order 0..63 — identical association to the round-1 passing kernel. */
__global__ __launch_bounds__(128) void k_off(const float* __restrict__ fpchw,
                                             const float* __restrict__ offw,
                                             const float* __restrict__ offb,
                                             float* __restrict__ off) {
    const int cg = blockIdx.x, i = blockIdx.y, b = blockIdx.z, j = threadIdx.x;
    const int co0 = cg * CO_PER;
    __shared__ float sm[9 * HP];           /* 1224 floats = 4.9 KB */
    const float* slab = fpchw + ((size_t)(b * NC) * HP + i) * HP;  /* c=0 slab */
    double acc[CO_PER];
#pragma unroll
    for (int u = 0; u < CO_PER; ++u) acc[u] = 0.0;

    float4 r0, r1, r2;
    {
        const float4* s4 = (const float4*)slab;
        r0 = s4[j];
        r1 = s4[j + 128];
        if (j < 50) r2 = s4[j + 256];
    }
    for (int c = 0; c < 64; ++c) {
        __syncthreads();
        {
            float4* d4 = (float4*)sm;
            d4[j] = r0;
            d4[j + 128] = r1;
            if (j < 50) d4[j + 256] = r2;
        }
        if (c + 1 < 64) {
            const float4* s4 = (const float4*)(slab + (size_t)(c + 1) * PADPIX);
            r0 = s4[j];
            r1 = s4[j + 128];
            if (j < 50) r2 = s4[j + 256];
        }
        __syncthreads();
        const float* wb = offw + (size_t)c * 81;
        float p[CO_PER];
#pragma unroll
        for (int u = 0; u < CO_PER; ++u) p[u] = 0.f;
#pragma unroll
        for (int ky = 0; ky < 9; ++ky) {
            float v[9];
#pragma unroll
            for (int kx = 0; kx < 9; ++kx) v[kx] = sm[ky * HP + j + kx];
#pragma unroll
            for (int u = 0; u < CO_PER; ++u) {
                const float* w = wb + (size_t)(co0 + u) * 64 * 81 + ky * 9;
#pragma unroll
                for (int kx = 0; kx < 9; ++kx)
                    p[u] = fmaf(v[kx], w[kx], p[u]);
            }
        }
#pragma unroll
        for (int u = 0; u < CO_PER; ++u) acc[u] += (double)p[u];
    }
#pragma unroll
    for (int u = 0; u < CO_PER; ++u)
        off[((b * NCH + co0 + u) << 14) + (i << 7) + j] = (float)acc[u] + offb[co0 + u];
}

/* per-channel mean / rsqrt(var+eps) in double */
__global__ __launch_bounds__(256) void k_stats(const float* __restrict__ off,
                                               float* __restrict__ stats) {
    int ch = blockIdx.x, t = threadIdx.x;
    double s = 0.0, ss = 0.0;
    for (int p = t; p < NB * NPIX; p += 256) {
        int b = p >> 14, q = p & 16383;
        float v = off[((b * NCH + ch) << 14) + q];
        s += (double)v;
        ss += (double)v * (double)v;
    }
    __shared__ double sh1[256], sh2[256];
    sh1[t] = s; sh2[t] = ss;
    __syncthreads();
    for (int st = 128; st > 0; st >>= 1) {
        if (t < st) { sh1[t] += sh1[t + st]; sh2[t] += sh2[t + st]; }
        __syncthreads();
    }
    if (t == 0) {
        double n = (double)(NB * NPIX);
        double m = sh1[0] / n;
        double var = sh2[0] / n - m * m;
        stats[ch] = (float)m;
        stats[NCH + ch] = (float)(1.0 / sqrt(var + 1e-5));
    }
}

/* BN + tanh + cum + floor -> gather row indices (reproduces base-stride bug) */
__global__ __launch_bounds__(128) void k_idx(const float* __restrict__ off,
                                             const float* __restrict__ stats,
                                             const float* __restrict__ gamma,
                                             const float* __restrict__ beta,
                                             int* __restrict__ r2, int* __restrict__ r3) {
    int i = blockIdx.x, b = blockIdx.y, j = threadIdx.x;
    float tt[NCH];
#pragma unroll
    for (int ch = 0; ch < NCH; ++ch) {
        float v = off[((b * NCH + ch) << 14) + (i << 7) + j];
        v = (v - stats[ch]) * stats[NCH + ch];
        v = v * gamma[ch] + beta[ch];
        tt[ch] = (float)tanh((double)v);
    }
    /* cum(): [0, h1, h2, h3, mid, t5, t6, t7, 0] with reference association */
    float cz[9], cw[9];
    {
        const float* o = tt;
        cz[0] = 0.f;
        cz[1] = o[1];
        cz[2] = o[1] + o[2];
        cz[3] = (o[1] + o[2]) + o[3];
        cz[7] = o[7];
        cz[6] = o[7] + o[6];
        cz[5] = (o[7] + o[6]) + o[5];
        cz[4] = (cz[3] + cz[5]) * 0.5f;
        cz[8] = 0.f;
    }
    {
        const float* o = tt + 9;
        cw[0] = 0.f;
        cw[1] = o[1];
        cw[2] = o[1] + o[2];
        cw[3] = (o[1] + o[2]) + o[3];
        cw[7] = o[7];
        cw[6] = o[7] + o[6];
        cw[5] = (o[7] + o[6]) + o[5];
        cw[4] = (cw[3] + cw[5]) * 0.5f;
        cw[8] = 0.f;
    }
    const int rmax = NB * PADPIX - 1;
#pragma unroll
    for (int k = 0; k < 9; ++k) {
        int iy2 = (int)floorf((float)(i + 8 - k) + cz[k]);
        int ix2 = (int)floorf((float)(j + k) + cz[k]);
        int rr = b * 16384 + iy2 * HP + ix2;
        rr = rr < 0 ? 0 : (rr > rmax ? rmax : rr);
        r2[((b * 9 + k) << 14) + (i << 7) + j] = rr;
        int iy3 = (int)floorf((float)(i + k) + cw[k]);
        int ix3 = (int)floorf((float)(j + k) - cw[k]);
        int r3v = b * 16384 + iy3 * HP + ix3;
        r3v = r3v < 0 ? 0 : (r3v > rmax ? rmax : r3v);
        r3[((b * 9 + k) << 14) + (i << 7) + j] = r3v;
    }
}

/* main gathered strip-convs: per block 64 positions x 64 out-ch, Kdim = 18*64 */
__global__ __launch_bounds__(256) void k_main(const float* __restrict__ fpflat,
                                              const int* __restrict__ r2,
                                              const int* __restrict__ r3,
                                              const float* __restrict__ wx,
                                              const float* __restrict__ wy,
                                              const float* __restrict__ bx,
                                              const float* __restrict__ by,
                                              float* __restrict__ out) {
    __shared__ float sA[64 * 64];  /* [c][j] */
    __shared__ float sW[64 * 64];  /* [c][o] */
    int b = blockIdx.z, i = blockIdx.y;
    int j0 = blockIdx.x * 64;
    int t = threadIdx.x;
    int jt = t & 15;
    int ot = t >> 4;
    float acc[4][4];
#pragma unroll
    for (int a = 0; a < 4; ++a)
#pragma unroll
        for (int bb = 0; bb < 4; ++bb) acc[a][bb] = 0.f;

    int sj = t >> 2;
    int cq = t & 3;

    for (int q = 0; q < 18; ++q) {
        int k = (q < 9) ? q : (q - 9);
        const int* rr = ((q < 9) ? r2 : r3) + (((b * 9 + k) << 14) + (i << 7) + j0);
        const float* wsrc = ((q < 9) ? wx : wy) + k * 4096;
        __syncthreads();
        {
            const float4* s4 = (const float4*)wsrc;
            float4* d4 = (float4*)sW;
#pragma unroll
            for (int u = 0; u < 4; ++u) d4[t + 256 * u] = s4[t + 256 * u];
        }
        {
            int row = rr[sj];
            const float* src = fpflat + (size_t)row * 64;
#pragma unroll
            for (int u = 0; u < 4; ++u) {
                int c0 = cq * 16 + u * 4;
                float4 v = *(const float4*)(src + c0);
                sA[(c0 + 0) * 64 + sj] = v.x;
                sA[(c0 + 1) * 64 + sj] = v.y;
                sA[(c0 + 2) * 64 + sj] = v.z;
                sA[(c0 + 3) * 64 + sj] = v.w;
            }
        }
        __syncthreads();
#pragma unroll 4
        for (int c = 0; c < 64; ++c) {
            float4 a4 = *(const float4*)&sA[c * 64 + jt * 4];
            float4 w4 = *(const float4*)&sW[c * 64 + ot * 4];
            const float av[4] = {a4.x, a4.y, a4.z, a4.w};
            const float wv[4] = {w4.x, w4.y, w4.z, w4.w};
#pragma unroll
            for (int jj = 0; jj < 4; ++jj)
#pragma unroll
                for (int oo = 0; oo < 4; ++oo)
                    acc[jj][oo] = fmaf(av[jj], wv[oo], acc[jj][oo]);
        }
    }
#pragma unroll
    for (int oo = 0; oo < 4; ++oo) {
        int o = ot * 4 + oo;
        float bias = bx[o] + by[o];
#pragma unroll
        for (int jj = 0; jj < 4; ++jj) {
            int j = j0 + jt * 4 + jj;
            out[(((b * NO + o) << 7) + i) * NH + j] = acc[jj][oo] + bias;
        }
    }
}

extern "C" void kernel_launch(void* const* d_in, const int* in_sizes, int n_in,
                              void* d_out, int out_size, void* d_ws, size_t ws_size,
                              hipStream_t stream) {
    const float* f     = (const float*)d_in[0];
    const float* offw  = (const float*)d_in[1];
    const float* offb  = (const float*)d_in[2];
    const float* gamma = (const float*)d_in[3];
    const float* beta  = (const float*)d_in[4];
    const float* cwx   = (const float*)d_in[5];
    const float* cbx   = (const float*)d_in[6];
    const float* cwy   = (const float*)d_in[7];
    const float* cby   = (const float*)d_in[8];
    float* ws = (float*)d_ws;
    float* fpchw  = ws + O_FPCHW;
    float* fpflat = ws + O_FPFLAT;
    float* off    = ws + O_OFF;
    float* stats  = ws + O_STATS;
    float* wx     = ws + O_WX;
    float* wy     = ws + O_WY;
    int*   r2     = (int*)(ws + O_R2);
    int*   r3     = (int*)(ws + O_R3);
    float* out    = (float*)d_out;

    {
        int n4 = (2 * SZ_FP) / 4;
        k_zero<<<(n4 + 255) / 256, 256, 0, stream>>>((float4*)fpchw, n4);
    }
    k_pad<<<(NB * NC * NPIX + 255) / 256, 256, 0, stream>>>(f, fpchw, fpflat);
    k_wt<<<(KK * 64 * 64 + 255) / 256, 256, 0, stream>>>(cwx, cwy, wx, wy);
    k_off<<<dim3(3, NH, NB), 128, 0, stream>>>(fpchw, offw, offb, off);
    k_stats<<<NCH, 256, 0, stream>>>(off, stats);
    k_idx<<<dim3(NH, NB), 128, 0, stream>>>(off, stats, gamma, beta, r2, r3);
    k_main<<<dim3(2, NH, NB), 256, 0, stream>>>(fpflat, r2, r3, wx, wy, cbx, cby, out);
}

// Round 3
// 645.982 us; speedup vs baseline: 1.5358x; 1.0999x over previous
//
#include <hip/hip_runtime.h>
#include <math.h>

#define KK 9
#define NB 4
#define NC 64
#define NO 64
#define NH 128
#define HP 136
#define NPIX (NH*NH)     /* 16384 */
#define PADPIX (HP*HP)   /* 18496 */
#define NCH 18
#define CO_PER 6         /* offset-conv output channels per block */

/* workspace layout (float offsets) */
#define SZ_FP    (NB*NC*PADPIX)        /* 4,734,976 */
#define O_FPCHW  0
#define O_FPFLAT (O_FPCHW + SZ_FP)
#define O_OFF    (O_FPFLAT + SZ_FP)
#define SZ_OFF   (NB*NCH*NPIX)         /* 1,179,648 */
#define O_STATS  (O_OFF + SZ_OFF)
#define O_WX     (O_STATS + 64)
#define O_WY     (O_WX + KK*64*64)
#define O_R2     (O_WY + KK*64*64)
#define SZ_R     (NB*KK*NPIX)          /* 589,824 */
#define O_R3     (O_R2 + SZ_R)
#define WS_FLOATS (O_R3 + SZ_R)        /* ~11.9M floats = 47.6 MB */
/* repacked offset weights [c][ky][co][12]: 64*9*18*12 = 124,416 floats.
   Lives in the r2 region: written by k_wt (before k_off), dead after k_off;
   r2 itself is only written by k_idx which runs after k_off. */
#define O_WR     O_R2
#define WR_CH_STRIDE (9*18*12)   /* 1944 floats per channel */

__global__ void k_zero(float4* p, int n4) {
    int id = blockIdx.x * 256 + threadIdx.x;
    if (id < n4) p[id] = make_float4(0.f, 0.f, 0.f, 0.f);
}

/* fill both padded layouts of f */
__global__ void k_pad(const float* __restrict__ f, float* __restrict__ fpchw,
                      float* __restrict__ fpflat) {
    int id = blockIdx.x * 256 + threadIdx.x;
    if (id >= NB * NC * NPIX) return;
    int w = id & 127;
    int h = (id >> 7) & 127;
    int c = (id >> 14) & 63;
    int b = id >> 20;
    float v = f[id];
    fpchw[((b * NC + c) * HP + (h + 4)) * HP + (w + 4)] = v;
    fpflat[(((b * HP + (h + 4)) * HP) + (w + 4)) * NC + c] = v;
}

/* transpose main-conv weights to [k][c][o]  AND  repack offset weights
   to wr[c][ky][co][12] (kx padded 9->12 for 16B-aligned ds_read_b128). */
__global__ void k_wt(const float* __restrict__ cwx, const float* __restrict__ cwy,
                     const float* __restrict__ offw,
                     float* __restrict__ wx, float* __restrict__ wy,
                     float* __restrict__ wr) {
    int id = blockIdx.x * 256 + threadIdx.x;
    if (id < KK * 64 * 64) {
        int o = id & 63;
        int c = (id >> 6) & 63;
        int k = id >> 12;
        wx[id] = cwx[(o * 64 + c) * 9 + k];
        wy[id] = cwy[(o * 64 + c) * 9 + k];
    }
    if (id < 18 * 64 * 9 * 9) {
        int kx = id % 9;
        int r = id / 9;
        int ky = r % 9; r /= 9;
        int c = r % 64;
        int co = r / 64;
        wr[((c * 9 + ky) * 18 + co) * 12 + kx] =
            offw[((co * 64 + c) * 9 + ky) * 9 + kx];
    }
}

/* offset conv, LDS-staged slab AND LDS-staged weights (broadcast ds reads).
   block = (co-group of 6, row i, batch b), 128 thr = j.
   Inner loop touches ONLY ds ops (no s_load of weights) so lgkmcnt stays
   fine-grained. Association identical to round-1 passing kernel:
   per-(co,c) fp32 tap chain in (ky,kx) order, double-accumulated over c. */
__global__ __launch_bounds__(128) void k_off(const float* __restrict__ fpchw,
                                             const float* __restrict__ wr,
                                             const float* __restrict__ offb,
                                             float* __restrict__ off) {
    const int cg = blockIdx.x, i = blockIdx.y, b = blockIdx.z, j = threadIdx.x;
    const int co0 = cg * CO_PER;
    __shared__ float sm[9 * HP];           /* 1224 floats */
    __shared__ float lw[CO_PER * 9 * 12];  /* 648 floats: [ky][u][12] */
    const float* slab = fpchw + ((size_t)(b * NC) * HP + i) * HP;  /* c=0 */
    double acc[CO_PER];
#pragma unroll
    for (int u = 0; u < CO_PER; ++u) acc[u] = 0.0;

    /* weight prefetch addressing: float4 q = j and q = j+128 (j<34).
       q -> ky = q/18, within = q%18; src float = c*1944 + ky*216 + co0*12 + within*4 */
    const int qa_ky = j / 18, qa_wi = j - qa_ky * 18;
    const int base_a = qa_ky * 216 + co0 * 12 + qa_wi * 4;
    const int qb = j + 128;
    const int qb_ky = qb / 18, qb_wi = qb - qb_ky * 18;
    const int base_b = qb_ky * 216 + co0 * 12 + qb_wi * 4;

    float4 r0, r1, r2, wA, wB;
    {
        const float4* s4 = (const float4*)slab;
        r0 = s4[j];
        r1 = s4[j + 128];
        if (j < 50) r2 = s4[j + 256];
        wA = *(const float4*)(wr + base_a);
        if (j < 34) wB = *(const float4*)(wr + base_b);
    }
    for (int c = 0; c < 64; ++c) {
        __syncthreads();
        {
            float4* d4 = (float4*)sm;
            d4[j] = r0;
            d4[j + 128] = r1;
            if (j < 50) d4[j + 256] = r2;
            float4* l4 = (float4*)lw;
            l4[j] = wA;
            if (j < 34) l4[j + 128] = wB;
        }
        if (c + 1 < 64) {
            const float4* s4 = (const float4*)(slab + (size_t)(c + 1) * PADPIX);
            r0 = s4[j];
            r1 = s4[j + 128];
            if (j < 50) r2 = s4[j + 256];
            const float* wc = wr + (size_t)(c + 1) * WR_CH_STRIDE;
            wA = *(const float4*)(wc + base_a);
            if (j < 34) wB = *(const float4*)(wc + base_b);
        }
        __syncthreads();
        float p[CO_PER];
#pragma unroll
        for (int u = 0; u < CO_PER; ++u) p[u] = 0.f;
#pragma unroll
        for (int ky = 0; ky < 9; ++ky) {
            float v[9];
#pragma unroll
            for (int kx = 0; kx < 9; ++kx) v[kx] = sm[ky * HP + j + kx];
#pragma unroll
            for (int u = 0; u < CO_PER; ++u) {
                const float* wp = lw + (ky * CO_PER + u) * 12;
                float4 w0 = *(const float4*)(wp);
                float4 w1 = *(const float4*)(wp + 4);
                float4 w2 = *(const float4*)(wp + 8);
                float pu = p[u];
                pu = fmaf(v[0], w0.x, pu);
                pu = fmaf(v[1], w0.y, pu);
                pu = fmaf(v[2], w0.z, pu);
                pu = fmaf(v[3], w0.w, pu);
                pu = fmaf(v[4], w1.x, pu);
                pu = fmaf(v[5], w1.y, pu);
                pu = fmaf(v[6], w1.z, pu);
                pu = fmaf(v[7], w1.w, pu);
                pu = fmaf(v[8], w2.x, pu);
                p[u] = pu;
            }
        }
#pragma unroll
        for (int u = 0; u < CO_PER; ++u) acc[u] += (double)p[u];
    }
#pragma unroll
    for (int u = 0; u < CO_PER; ++u)
        off[((b * NCH + co0 + u) << 14) + (i << 7) + j] = (float)acc[u] + offb[co0 + u];
}

/* per-channel mean / rsqrt(var+eps) in double */
__global__ __launch_bounds__(256) void k_stats(const float* __restrict__ off,
                                               float* __restrict__ stats) {
    int ch = blockIdx.x, t = threadIdx.x;
    double s = 0.0, ss = 0.0;
    for (int p = t; p < NB * NPIX; p += 256) {
        int b = p >> 14, q = p & 16383;
        float v = off[((b * NCH + ch) << 14) + q];
        s += (double)v;
        ss += (double)v * (double)v;
    }
    __shared__ double sh1[256], sh2[256];
    sh1[t] = s; sh2[t] = ss;
    __syncthreads();
    for (int st = 128; st > 0; st >>= 1) {
        if (t < st) { sh1[t] += sh1[t + st]; sh2[t] += sh2[t + st]; }
        __syncthreads();
    }
    if (t == 0) {
        double n = (double)(NB * NPIX);
        double m = sh1[0] / n;
        double var = sh2[0] / n - m * m;
        stats[ch] = (float)m;
        stats[NCH + ch] = (float)(1.0 / sqrt(var + 1e-5));
    }
}

/* BN + tanh + cum + floor -> gather row indices (reproduces base-stride bug) */
__global__ __launch_bounds__(128) void k_idx(const float* __restrict__ off,
                                             const float* __restrict__ stats,
                                             const float* __restrict__ gamma,
                                             const float* __restrict__ beta,
                                             int* __restrict__ r2, int* __restrict__ r3) {
    int i = blockIdx.x, b = blockIdx.y, j = threadIdx.x;
    float tt[NCH];
#pragma unroll
    for (int ch = 0; ch < NCH; ++ch) {
        float v = off[((b * NCH + ch) << 14) + (i << 7) + j];
        v = (v - stats[ch]) * stats[NCH + ch];
        v = v * gamma[ch] + beta[ch];
        tt[ch] = (float)tanh((double)v);
    }
    float cz[9], cw[9];
    {
        const float* o = tt;
        cz[0] = 0.f;
        cz[1] = o[1];
        cz[2] = o[1] + o[2];
        cz[3] = (o[1] + o[2]) + o[3];
        cz[7] = o[7];
        cz[6] = o[7] + o[6];
        cz[5] = (o[7] + o[6]) + o[5];
        cz[4] = (cz[3] + cz[5]) * 0.5f;
        cz[8] = 0.f;
    }
    {
        const float* o = tt + 9;
        cw[0] = 0.f;
        cw[1] = o[1];
        cw[2] = o[1] + o[2];
        cw[3] = (o[1] + o[2]) + o[3];
        cw[7] = o[7];
        cw[6] = o[7] + o[6];
        cw[5] = (o[7] + o[6]) + o[5];
        cw[4] = (cw[3] + cw[5]) * 0.5f;
        cw[8] = 0.f;
    }
    const int rmax = NB * PADPIX - 1;
#pragma unroll
    for (int k = 0; k < 9; ++k) {
        int iy2 = (int)floorf((float)(i + 8 - k) + cz[k]);
        int ix2 = (int)floorf((float)(j + k) + cz[k]);
        int rr = b * 16384 + iy2 * HP + ix2;
        rr = rr < 0 ? 0 : (rr > rmax ? rmax : rr);
        r2[((b * 9 + k) << 14) + (i << 7) + j] = rr;
        int iy3 = (int)floorf((float)(i + k) + cw[k]);
        int ix3 = (int)floorf((float)(j + k) - cw[k]);
        int r3v = b * 16384 + iy3 * HP + ix3;
        r3v = r3v < 0 ? 0 : (r3v > rmax ? rmax : r3v);
        r3[((b * 9 + k) << 14) + (i << 7) + j] = r3v;
    }
}

/* main gathered strip-convs: per block 64 positions x 64 out-ch, Kdim = 18*64 */
__global__ __launch_bounds__(256) void k_main(const float* __restrict__ fpflat,
                                              const int* __restrict__ r2,
                                              const int* __restrict__ r3,
                                              const float* __restrict__ wx,
                                              const float* __restrict__ wy,
                                              const float* __restrict__ bx,
                                              const float* __restrict__ by,
                                              float* __restrict__ out) {
    __shared__ float sA[64 * 64];  /* [c][j] */
    __shared__ float sW[64 * 64];  /* [c][o] */
    int b = blockIdx.z, i = blockIdx.y;
    int j0 = blockIdx.x * 64;
    int t = threadIdx.x;
    int jt = t & 15;
    int ot = t >> 4;
    float acc[4][4];
#pragma unroll
    for (int a = 0; a < 4; ++a)
#pragma unroll
        for (int bb = 0; bb < 4; ++bb) acc[a][bb] = 0.f;

    int sj = t >> 2;
    int cq = t & 3;

    for (int q = 0; q < 18; ++q) {
        int k = (q < 9) ? q : (q - 9);
        const int* rr = ((q < 9) ? r2 : r3) + (((b * 9 + k) << 14) + (i << 7) + j0);
        const float* wsrc = ((q < 9) ? wx : wy) + k * 4096;
        __syncthreads();
        {
            const float4* s4 = (const float4*)wsrc;
            float4* d4 = (float4*)sW;
#pragma unroll
            for (int u = 0; u < 4; ++u) d4[t + 256 * u] = s4[t + 256 * u];
        }
        {
            int row = rr[sj];
            const float* src = fpflat + (size_t)row * 64;
#pragma unroll
            for (int u = 0; u < 4; ++u) {
                int c0 = cq * 16 + u * 4;
                float4 v = *(const float4*)(src + c0);
                sA[(c0 + 0) * 64 + sj] = v.x;
                sA[(c0 + 1) * 64 + sj] = v.y;
                sA[(c0 + 2) * 64 + sj] = v.z;
                sA[(c0 + 3) * 64 + sj] = v.w;
            }
        }
        __syncthreads();
#pragma unroll 4
        for (int c = 0; c < 64; ++c) {
            float4 a4 = *(const float4*)&sA[c * 64 + jt * 4];
            float4 w4 = *(const float4*)&sW[c * 64 + ot * 4];
            const float av[4] = {a4.x, a4.y, a4.z, a4.w};
            const float wv[4] = {w4.x, w4.y, w4.z, w4.w};
#pragma unroll
            for (int jj = 0; jj < 4; ++jj)
#pragma unroll
                for (int oo = 0; oo < 4; ++oo)
                    acc[jj][oo] = fmaf(av[jj], wv[oo], acc[jj][oo]);
        }
    }
#pragma unroll
    for (int oo = 0; oo < 4; ++oo) {
        int o = ot * 4 + oo;
        float bias = bx[o] + by[o];
#pragma unroll
        for (int jj = 0; jj < 4; ++jj) {
            int j = j0 + jt * 4 + jj;
            out[(((b * NO + o) << 7) + i) * NH + j] = acc[jj][oo] + bias;
        }
    }
}

extern "C" void kernel_launch(void* const* d_in, const int* in_sizes, int n_in,
                              void* d_out, int out_size, void* d_ws, size_t ws_size,
                              hipStream_t stream) {
    const float* f     = (const float*)d_in[0];
    const float* offw  = (const float*)d_in[1];
    const float* offb  = (const float*)d_in[2];
    const float* gamma = (const float*)d_in[3];
    const float* beta  = (const float*)d_in[4];
    const float* cwx   = (const float*)d_in[5];
    const float* cbx   = (const float*)d_in[6];
    const float* cwy   = (const float*)d_in[7];
    const float* cby   = (const float*)d_in[8];
    float* ws = (float*)d_ws;
    float* fpchw  = ws + O_FPCHW;
    float* fpflat = ws + O_FPFLAT;
    float* off    = ws + O_OFF;
    float* stats  = ws + O_STATS;
    float* wx     = ws + O_WX;
    float* wy     = ws + O_WY;
    float* wr     = ws + O_WR;       /* overlaps r2: dead before k_idx writes */
    int*   r2     = (int*)(ws + O_R2);
    int*   r3     = (int*)(ws + O_R3);
    float* out    = (float*)d_out;

    {
        int n4 = (2 * SZ_FP) / 4;
        k_zero<<<(n4 + 255) / 256, 256, 0, stream>>>((float4*)fpchw, n4);
    }
    k_pad<<<(NB * NC * NPIX + 255) / 256, 256, 0, stream>>>(f, fpchw, fpflat);
    k_wt<<<(18 * 64 * 81 + 255) / 256, 256, 0, stream>>>(cwx, cwy, offw, wx, wy, wr);
    k_off<<<dim3(3, NH, NB), 128, 0, stream>>>(fpchw, wr, offb, off);
    k_stats<<<NCH, 256, 0, stream>>>(off, stats);
    k_idx<<<dim3(NH, NB), 128, 0, stream>>>(off, stats, gamma, beta, r2, r3);
    k_main<<<dim3(2, NH, NB), 256, 0, stream>>>(fpflat, r2, r3, wx, wy, cbx, cby, out);
}

// Round 4
// 508.475 us; speedup vs baseline: 1.9511x; 1.2704x over previous
//
#include <hip/hip_runtime.h>
#include <math.h>

#define KK 9
#define NB 4
#define NC 64
#define NO 64
#define NH 128
#define HP 136
#define NPIX (NH*NH)     /* 16384 */
#define PADPIX (HP*HP)   /* 18496 */
#define NCH 18
#define CO_PER 6         /* offset-conv output channels per block */

/* workspace layout (float offsets) */
#define SZ_FP    (NB*NC*PADPIX)        /* 4,734,976 */
#define O_FPCHW  0
#define O_FPFLAT (O_FPCHW + SZ_FP)
#define O_OFF    (O_FPFLAT + SZ_FP)
#define SZ_OFF   (NB*NCH*NPIX)         /* 1,179,648 */
#define O_STATS  (O_OFF + SZ_OFF)
#define O_WX     (O_STATS + 64)
#define O_WY     (O_WX + KK*64*64)
#define O_R2     (O_WY + KK*64*64)
#define SZ_R     (NB*KK*NPIX)          /* 589,824 */
#define O_R3     (O_R2 + SZ_R)
/* repacked offset weights [c][cg][ky][u6][12]: 64*3*9*72 = 124,416 floats,
   placed AFTER r3 (live through k_off; r2/r3 double as k_off half-0 partial
   storage, both dead before k_idx writes them). */
#define O_WR     (O_R3 + SZ_R)
#define WR_CH_STRIDE (3*9*72)    /* 1944 floats per input channel */
#define WS_FLOATS (O_WR + 64*WR_CH_STRIDE)   /* ~12.03M floats = 48.1 MB */

__global__ void k_zero(float4* p, int n4) {
    int id = blockIdx.x * 256 + threadIdx.x;
    if (id < n4) p[id] = make_float4(0.f, 0.f, 0.f, 0.f);
}

/* padded layouts of f: LDS-tiled so BOTH writes are coalesced */
__global__ __launch_bounds__(256) void k_pad(const float* __restrict__ f,
                                             float* __restrict__ fpchw,
                                             float* __restrict__ fpflat) {
    __shared__ float tile[64][65];   /* [c][w] */
    const int wt = blockIdx.x, h = blockIdx.y, b = blockIdx.z;
    const int w0 = wt * 64;
    const int tc = threadIdx.x >> 6;   /* 0..3 */
    const int tw = threadIdx.x & 63;
    for (int cc = tc; cc < 64; cc += 4) {
        float v = f[((b * 64 + cc) * 128 + h) * 128 + w0 + tw];
        tile[cc][tw] = v;
        fpchw[((b * 64 + cc) * HP + h + 4) * HP + w0 + tw + 4] = v;
    }
    __syncthreads();
    for (int pp = tc; pp < 64; pp += 4) {
        fpflat[(((b * HP + h + 4) * HP) + w0 + pp + 4) * 64 + tw] = tile[tw][pp];
    }
}

/* transpose main-conv weights to [k][c][o] AND repack offset weights to
   wr[c][cg][ky][u][12] (kx padded 9->12 for aligned ds_read_b128). */
__global__ void k_wt(const float* __restrict__ cwx, const float* __restrict__ cwy,
                     const float* __restrict__ offw,
                     float* __restrict__ wx, float* __restrict__ wy,
                     float* __restrict__ wr) {
    int id = blockIdx.x * 256 + threadIdx.x;
    if (id < KK * 64 * 64) {
        int o = id & 63;
        int c = (id >> 6) & 63;
        int k = id >> 12;
        wx[id] = cwx[(o * 64 + c) * 9 + k];
        wy[id] = cwy[(o * 64 + c) * 9 + k];
    }
    if (id < 18 * 64 * 9 * 9) {
        int kx = id % 9;
        int r = id / 9;
        int ky = r % 9; r /= 9;
        int c = r % 64;
        int co = r / 64;
        int cg = co / 6, u = co - cg * 6;
        wr[((((c * 3 + cg) * 9) + ky) * 6 + u) * 12 + kx] =
            offw[((co * 64 + c) * 9 + ky) * 9 + kx];
    }
}

/* offset conv, 4-j-strip x 6-co per thread, channel-halved.
   block = 128 thr: tr = t>>5 (row 0..3), tj = t&31 (j0 = 4*tj).
   grid = (cg 3, igroup 32, b*2+half).
   Per channel: stage 12x136 input slab + 648-float weight slice in LDS
   (register-prefetched); inner loop: 3 input b128 + 18 weight-broadcast b128
   feed 216 FMAs per ky. Association identical to the passing kernel:
   per-(co,c) fp32 tap chain ky->kx, double accumulation over ascending c. */
__global__ __launch_bounds__(128) void k_off(const float* __restrict__ fpchw,
                                             const float* __restrict__ wr,
                                             float* __restrict__ pp0,
                                             float* __restrict__ off) {
    const int cg = blockIdx.x, ig = blockIdx.y;
    const int b = blockIdx.z >> 1, half = blockIdx.z & 1;
    const int t = threadIdx.x;
    const int tr = t >> 5, tj = t & 31;
    const int i0 = ig * 4, j0 = tj * 4, c0 = half * 32, co0 = cg * CO_PER;
    float* pout = half ? off : pp0;

    __shared__ float sm[12 * HP];      /* 1632 floats */
    __shared__ float lw[6 * 9 * 12];   /* 648 floats: [ky][u][12] */

    const float* slab = fpchw + ((size_t)(b * 64 + c0) * HP + i0) * HP;
    const float* wsl  = wr + (size_t)c0 * WR_CH_STRIDE + (size_t)cg * (9 * 72);

    double acc[CO_PER][4];
#pragma unroll
    for (int u = 0; u < CO_PER; ++u)
#pragma unroll
        for (int jj = 0; jj < 4; ++jj) acc[u][jj] = 0.0;

    float4 r0, r1, r2, r3, wA, wB;
    {
        const float4* s4 = (const float4*)slab;
        r0 = s4[t]; r1 = s4[t + 128]; r2 = s4[t + 256];
        if (t < 24) r3 = s4[t + 384];
        const float4* w4 = (const float4*)wsl;
        wA = w4[t];
        if (t < 34) wB = w4[t + 128];
    }
    for (int c = 0; c < 32; ++c) {
        __syncthreads();
        {
            float4* d4 = (float4*)sm;
            d4[t] = r0; d4[t + 128] = r1; d4[t + 256] = r2;
            if (t < 24) d4[t + 384] = r3;
            float4* l4 = (float4*)lw;
            l4[t] = wA;
            if (t < 34) l4[t + 128] = wB;
        }
        if (c + 1 < 32) {
            const float4* s4 = (const float4*)(slab + (size_t)(c + 1) * PADPIX);
            r0 = s4[t]; r1 = s4[t + 128]; r2 = s4[t + 256];
            if (t < 24) r3 = s4[t + 384];
            const float4* w4 = (const float4*)(wsl + (size_t)(c + 1) * WR_CH_STRIDE);
            wA = w4[t];
            if (t < 34) wB = w4[t + 128];
        }
        __syncthreads();
        float p[CO_PER][4];
#pragma unroll
        for (int u = 0; u < CO_PER; ++u)
#pragma unroll
            for (int jj = 0; jj < 4; ++jj) p[u][jj] = 0.f;
#pragma unroll
        for (int ky = 0; ky < 9; ++ky) {
            const float4* s4 = (const float4*)sm;
            int b4 = (tr + ky) * 34 + tj;
            float4 va = s4[b4], vb = s4[b4 + 1], vc = s4[b4 + 2];
            float v[12] = {va.x, va.y, va.z, va.w, vb.x, vb.y, vb.z, vb.w,
                           vc.x, vc.y, vc.z, vc.w};
#pragma unroll
            for (int u = 0; u < CO_PER; ++u) {
                const float* wp = lw + (ky * CO_PER + u) * 12;
                float4 w0 = *(const float4*)(wp);
                float4 w1 = *(const float4*)(wp + 4);
                float4 w2 = *(const float4*)(wp + 8);
                const float w[9] = {w0.x, w0.y, w0.z, w0.w,
                                    w1.x, w1.y, w1.z, w1.w, w2.x};
#pragma unroll
                for (int jj = 0; jj < 4; ++jj) {
                    float pu = p[u][jj];
#pragma unroll
                    for (int kx = 0; kx < 9; ++kx)
                        pu = fmaf(v[kx + jj], w[kx], pu);
                    p[u][jj] = pu;
                }
            }
        }
#pragma unroll
        for (int u = 0; u < CO_PER; ++u)
#pragma unroll
            for (int jj = 0; jj < 4; ++jj) acc[u][jj] += (double)p[u][jj];
    }
#pragma unroll
    for (int u = 0; u < CO_PER; ++u)
#pragma unroll
        for (int jj = 0; jj < 4; ++jj)
            pout[((b * NCH + co0 + u) << 14) + ((i0 + tr) << 7) + j0 + jj] =
                (float)acc[u][jj];
}

/* combine channel halves + bias: off = pp0(c0..31) + off(c32..63) + b */
__global__ void k_comb(float* __restrict__ off, const float* __restrict__ pp0,
                       const float* __restrict__ offb) {
    int x = blockIdx.x * 256 + threadIdx.x;
    if (x >= NB * NCH * NPIX) return;
    int ch = (x >> 14) % NCH;
    off[x] = pp0[x] + off[x] + offb[ch];
}

/* per-channel mean / rsqrt(var+eps) in double */
__global__ __launch_bounds__(256) void k_stats(const float* __restrict__ off,
                                               float* __restrict__ stats) {
    int ch = blockIdx.x, t = threadIdx.x;
    double s = 0.0, ss = 0.0;
    for (int p = t; p < NB * NPIX; p += 256) {
        int b = p >> 14, q = p & 16383;
        float v = off[((b * NCH + ch) << 14) + q];
        s += (double)v;
        ss += (double)v * (double)v;
    }
    __shared__ double sh1[256], sh2[256];
    sh1[t] = s; sh2[t] = ss;
    __syncthreads();
    for (int st = 128; st > 0; st >>= 1) {
        if (t < st) { sh1[t] += sh1[t + st]; sh2[t] += sh2[t + st]; }
        __syncthreads();
    }
    if (t == 0) {
        double n = (double)(NB * NPIX);
        double m = sh1[0] / n;
        double var = sh2[0] / n - m * m;
        stats[ch] = (float)m;
        stats[NCH + ch] = (float)(1.0 / sqrt(var + 1e-5));
    }
}

/* BN + tanh + cum + floor -> gather row indices (reproduces base-stride bug) */
__global__ __launch_bounds__(128) void k_idx(const float* __restrict__ off,
                                             const float* __restrict__ stats,
                                             const float* __restrict__ gamma,
                                             const float* __restrict__ beta,
                                             int* __restrict__ r2, int* __restrict__ r3) {
    int i = blockIdx.x, b = blockIdx.y, j = threadIdx.x;
    float tt[NCH];
#pragma unroll
    for (int ch = 0; ch < NCH; ++ch) {
        float v = off[((b * NCH + ch) << 14) + (i << 7) + j];
        v = (v - stats[ch]) * stats[NCH + ch];
        v = v * gamma[ch] + beta[ch];
        tt[ch] = (float)tanh((double)v);
    }
    float cz[9], cw[9];
    {
        const float* o = tt;
        cz[0] = 0.f;
        cz[1] = o[1];
        cz[2] = o[1] + o[2];
        cz[3] = (o[1] + o[2]) + o[3];
        cz[7] = o[7];
        cz[6] = o[7] + o[6];
        cz[5] = (o[7] + o[6]) + o[5];
        cz[4] = (cz[3] + cz[5]) * 0.5f;
        cz[8] = 0.f;
    }
    {
        const float* o = tt + 9;
        cw[0] = 0.f;
        cw[1] = o[1];
        cw[2] = o[1] + o[2];
        cw[3] = (o[1] + o[2]) + o[3];
        cw[7] = o[7];
        cw[6] = o[7] + o[6];
        cw[5] = (o[7] + o[6]) + o[5];
        cw[4] = (cw[3] + cw[5]) * 0.5f;
        cw[8] = 0.f;
    }
    const int rmax = NB * PADPIX - 1;
#pragma unroll
    for (int k = 0; k < 9; ++k) {
        int iy2 = (int)floorf((float)(i + 8 - k) + cz[k]);
        int ix2 = (int)floorf((float)(j + k) + cz[k]);
        int rr = b * 16384 + iy2 * HP + ix2;
        rr = rr < 0 ? 0 : (rr > rmax ? rmax : rr);
        r2[((b * 9 + k) << 14) + (i << 7) + j] = rr;
        int iy3 = (int)floorf((float)(i + k) + cw[k]);
        int ix3 = (int)floorf((float)(j + k) - cw[k]);
        int r3v = b * 16384 + iy3 * HP + ix3;
        r3v = r3v < 0 ? 0 : (r3v > rmax ? rmax : r3v);
        r3[((b * 9 + k) << 14) + (i << 7) + j] = r3v;
    }
}

/* main gathered strip-convs: per block 64 positions x 64 out-ch, Kdim = 18*64 */
__global__ __launch_bounds__(256) void k_main(const float* __restrict__ fpflat,
                                              const int* __restrict__ r2,
                                              const int* __restrict__ r3,
                                              const float* __restrict__ wx,
                                              const float* __restrict__ wy,
                                              const float* __restrict__ bx,
                                              const float* __restrict__ by,
                                              float* __restrict__ out) {
    __shared__ float sA[64 * 64];  /* [c][j] */
    __shared__ float sW[64 * 64];  /* [c][o] */
    int b = blockIdx.z, i = blockIdx.y;
    int j0 = blockIdx.x * 64;
    int t = threadIdx.x;
    int jt = t & 15;
    int ot = t >> 4;
    float acc[4][4];
#pragma unroll
    for (int a = 0; a < 4; ++a)
#pragma unroll
        for (int bb = 0; bb < 4; ++bb) acc[a][bb] = 0.f;

    int sj = t >> 2;
    int cq = t & 3;

    for (int q = 0; q < 18; ++q) {
        int k = (q < 9) ? q : (q - 9);
        const int* rr = ((q < 9) ? r2 : r3) + (((b * 9 + k) << 14) + (i << 7) + j0);
        const float* wsrc = ((q < 9) ? wx : wy) + k * 4096;
        __syncthreads();
        {
            const float4* s4 = (const float4*)wsrc;
            float4* d4 = (float4*)sW;
#pragma unroll
            for (int u = 0; u < 4; ++u) d4[t + 256 * u] = s4[t + 256 * u];
        }
        {
            int row = rr[sj];
            const float* src = fpflat + (size_t)row * 64;
#pragma unroll
            for (int u = 0; u < 4; ++u) {
                int c0 = cq * 16 + u * 4;
                float4 v = *(const float4*)(src + c0);
                sA[(c0 + 0) * 64 + sj] = v.x;
                sA[(c0 + 1) * 64 + sj] = v.y;
                sA[(c0 + 2) * 64 + sj] = v.z;
                sA[(c0 + 3) * 64 + sj] = v.w;
            }
        }
        __syncthreads();
#pragma unroll 4
        for (int c = 0; c < 64; ++c) {
            float4 a4 = *(const float4*)&sA[c * 64 + jt * 4];
            float4 w4 = *(const float4*)&sW[c * 64 + ot * 4];
            const float av[4] = {a4.x, a4.y, a4.z, a4.w};
            const float wv[4] = {w4.x, w4.y, w4.z, w4.w};
#pragma unroll
            for (int jj = 0; jj < 4; ++jj)
#pragma unroll
                for (int oo = 0; oo < 4; ++oo)
                    acc[jj][oo] = fmaf(av[jj], wv[oo], acc[jj][oo]);
        }
    }
#pragma unroll
    for (int oo = 0; oo < 4; ++oo) {
        int o = ot * 4 + oo;
        float bias = bx[o] + by[o];
#pragma unroll
        for (int jj = 0; jj < 4; ++jj) {
            int j = j0 + jt * 4 + jj;
            out[(((b * NO + o) << 7) + i) * NH + j] = acc[jj][oo] + bias;
        }
    }
}

extern "C" void kernel_launch(void* const* d_in, const int* in_sizes, int n_in,
                              void* d_out, int out_size, void* d_ws, size_t ws_size,
                              hipStream_t stream) {
    const float* f     = (const float*)d_in[0];
    const float* offw  = (const float*)d_in[1];
    const float* offb  = (const float*)d_in[2];
    const float* gamma = (const float*)d_in[3];
    const float* beta  = (const float*)d_in[4];
    const float* cwx   = (const float*)d_in[5];
    const float* cbx   = (const float*)d_in[6];
    const float* cwy   = (const float*)d_in[7];
    const float* cby   = (const float*)d_in[8];
    float* ws = (float*)d_ws;
    float* fpchw  = ws + O_FPCHW;
    float* fpflat = ws + O_FPFLAT;
    float* off    = ws + O_OFF;
    float* stats  = ws + O_STATS;
    float* wx     = ws + O_WX;
    float* wy     = ws + O_WY;
    float* wr     = ws + O_WR;
    float* pp0    = ws + O_R2;       /* half-0 partials, dead before k_idx */
    int*   r2     = (int*)(ws + O_R2);
    int*   r3     = (int*)(ws + O_R3);
    float* out    = (float*)d_out;

    {
        int n4 = (2 * SZ_FP) / 4;
        k_zero<<<(n4 + 255) / 256, 256, 0, stream>>>((float4*)fpchw, n4);
    }
    k_pad<<<dim3(2, NH, NB), 256, 0, stream>>>(f, fpchw, fpflat);
    k_wt<<<(18 * 64 * 81 + 255) / 256, 256, 0, stream>>>(cwx, cwy, offw, wx, wy, wr);
    k_off<<<dim3(3, 32, NB * 2), 128, 0, stream>>>(fpchw, wr, pp0, off);
    k_comb<<<(NB * NCH * NPIX + 255) / 256, 256, 0, stream>>>(off, pp0, offb);
    k_stats<<<NCH, 256, 0, stream>>>(off, stats);
    k_idx<<<dim3(NH, NB), 128, 0, stream>>>(off, stats, gamma, beta, r2, r3);
    k_main<<<dim3(2, NH, NB), 256, 0, stream>>>(fpflat, r2, r3, wx, wy, cbx, cby, out);
}